// Round 1
// baseline (132.786 us; speedup 1.0000x reference)
//
#include <hip/hip_runtime.h>

#define SCAN_BLOCK 256
#define EPT 16                      // elements (partitions) per thread
#define CHUNK (SCAN_BLOCK * EPT)    // 4096 elements per block

// ---------- Pass 1: count ones per chunk ----------
__global__ __launch_bounds__(SCAN_BLOCK)
void dps_count(const int* __restrict__ parts, int n, int* __restrict__ block_sums) {
    const int t  = threadIdx.x;
    const int e0 = blockIdx.x * CHUNK + t * EPT;
    int s = 0;
    if (e0 + EPT <= n) {
        const int4* p4 = reinterpret_cast<const int4*>(parts + e0);
        #pragma unroll
        for (int k = 0; k < EPT / 4; ++k) {
            int4 v = p4[k];
            s += v.x + v.y + v.z + v.w;
        }
    } else {
        for (int j = 0; j < EPT; ++j) {
            int i = e0 + j;
            if (i < n) s += parts[i];
        }
    }
    // wave64 reduce
    #pragma unroll
    for (int off = 32; off >= 1; off >>= 1) s += __shfl_down(s, off, 64);
    __shared__ int lds[SCAN_BLOCK / 64];
    if ((t & 63) == 0) lds[t >> 6] = s;
    __syncthreads();
    if (t == 0) {
        int tot = 0;
        #pragma unroll
        for (int w = 0; w < SCAN_BLOCK / 64; ++w) tot += lds[w];
        block_sums[blockIdx.x] = tot;
    }
}

// ---------- Pass 2: exclusive scan of block sums (nblocks <= SCAN_BLOCK) ----------
__global__ __launch_bounds__(SCAN_BLOCK)
void dps_scan(int* __restrict__ block_sums, int nblocks) {
    __shared__ int lds[SCAN_BLOCK];
    const int t = threadIdx.x;
    int v = (t < nblocks) ? block_sums[t] : 0;
    lds[t] = v;
    __syncthreads();
    for (int off = 1; off < SCAN_BLOCK; off <<= 1) {
        int add = (t >= off) ? lds[t - off] : 0;
        __syncthreads();
        lds[t] += add;
        __syncthreads();
    }
    if (t < nblocks) block_sums[t] = lds[t] - v;   // inclusive -> exclusive
}

// ---------- Pass 3: per-element rank -> invert permutation: src[dst] = i ----------
__global__ __launch_bounds__(SCAN_BLOCK)
void dps_rank(const int* __restrict__ parts,
              const int* __restrict__ index0,
              const int* __restrict__ index1,
              const int* __restrict__ block_excl,
              int n, int* __restrict__ src) {
    const int t  = threadIdx.x;
    const int e0 = blockIdx.x * CHUNK + t * EPT;
    int vals[EPT];
    int s = 0;
    if (e0 + EPT <= n) {
        const int4* p4 = reinterpret_cast<const int4*>(parts + e0);
        #pragma unroll
        for (int k = 0; k < EPT / 4; ++k) {
            int4 v = p4[k];
            vals[k * 4 + 0] = v.x; vals[k * 4 + 1] = v.y;
            vals[k * 4 + 2] = v.z; vals[k * 4 + 3] = v.w;
            s += v.x + v.y + v.z + v.w;
        }
    } else {
        for (int j = 0; j < EPT; ++j) {
            int i = e0 + j;
            vals[j] = (i < n) ? parts[i] : 0;
            s += vals[j];
        }
    }
    // block exclusive scan of per-thread sums
    __shared__ int lds[SCAN_BLOCK];
    lds[t] = s;
    __syncthreads();
    for (int off = 1; off < SCAN_BLOCK; off <<= 1) {
        int add = (t >= off) ? lds[t - off] : 0;
        __syncthreads();
        lds[t] += add;
        __syncthreads();
    }
    int ones_before = block_excl[blockIdx.x] + (lds[t] - s);  // global ones before e0
    #pragma unroll
    for (int j = 0; j < EPT; ++j) {
        int i = e0 + j;
        if (i < n) {
            // zeros before i == i - ones_before
            int dst = vals[j] ? index1[ones_before] : index0[i - ones_before];
            src[dst] = i;                 // 4-byte scatter (cheap); big copy stays streaming
            ones_before += vals[j];
        }
    }
}

// ---------- Pass 4: out[o] = data[src[o]]  (D==64 -> 16 float4 per row) ----------
__global__ __launch_bounds__(256)
void dps_gather(const float4* __restrict__ data4,
                const int* __restrict__ src,
                float4* __restrict__ out4,
                long total4) {
    long tid = (long)blockIdx.x * blockDim.x + threadIdx.x;
    if (tid >= total4) return;
    int row = (int)(tid >> 4);          // output row
    int q   = (int)(tid & 15);          // float4 within row
    int sr  = src[row];                 // broadcast across the 16 lanes of this row
    out4[tid] = data4[((long)sr << 4) + q];   // coalesced write, 256B-granular gather read
}

extern "C" void kernel_launch(void* const* d_in, const int* in_sizes, int n_in,
                              void* d_out, int out_size, void* d_ws, size_t ws_size,
                              hipStream_t stream) {
    const float* data   = (const float*)d_in[0];
    const int*   parts  = (const int*)d_in[1];
    const int*   index0 = (const int*)d_in[2];
    const int*   index1 = (const int*)d_in[3];
    const int n = in_sizes[1];                 // number of rows (partitions length)

    int* src        = (int*)d_ws;              // n ints
    int* block_sums = src + n;                 // nchunks ints

    const int nchunks = (n + CHUNK - 1) / CHUNK;   // 256 for n = 1<<20

    dps_count<<<nchunks, SCAN_BLOCK, 0, stream>>>(parts, n, block_sums);
    dps_scan <<<1,       SCAN_BLOCK, 0, stream>>>(block_sums, nchunks);
    dps_rank <<<nchunks, SCAN_BLOCK, 0, stream>>>(parts, index0, index1, block_sums, n, src);

    const long total4 = (long)n << 4;          // n * (64/4)
    const int  blocks = (int)((total4 + 255) / 256);
    dps_gather<<<blocks, 256, 0, stream>>>((const float4*)data, src, (float4*)d_out, total4);
}

// Round 2
// 116.801 us; speedup vs baseline: 1.1368x; 1.1368x over previous
//
#include <hip/hip_runtime.h>

#define SCAN_BLOCK 256
#define EPT 16                      // partition elements per thread
#define CHUNK (SCAN_BLOCK * EPT)    // 4096 elements per block

// ---------- Pass 1: count ones per chunk ----------
__global__ __launch_bounds__(SCAN_BLOCK)
void dps_count(const int* __restrict__ parts, int n, int* __restrict__ block_sums) {
    const int t  = threadIdx.x;
    const int e0 = blockIdx.x * CHUNK + t * EPT;
    int s = 0;
    if (e0 + EPT <= n) {
        const int4* p4 = reinterpret_cast<const int4*>(parts + e0);
        #pragma unroll
        for (int k = 0; k < EPT / 4; ++k) {
            int4 v = p4[k];
            s += v.x + v.y + v.z + v.w;
        }
    } else {
        for (int j = 0; j < EPT; ++j) {
            int i = e0 + j;
            if (i < n) s += parts[i];
        }
    }
    #pragma unroll
    for (int off = 32; off >= 1; off >>= 1) s += __shfl_down(s, off, 64);
    __shared__ int lds[SCAN_BLOCK / 64];
    if ((t & 63) == 0) lds[t >> 6] = s;
    __syncthreads();
    if (t == 0) {
        int tot = 0;
        #pragma unroll
        for (int w = 0; w < SCAN_BLOCK / 64; ++w) tot += lds[w];
        block_sums[blockIdx.x] = tot;
    }
}

// ---------- Pass 2: exclusive scan of block sums (nblocks <= SCAN_BLOCK) ----------
__global__ __launch_bounds__(SCAN_BLOCK)
void dps_scan(int* __restrict__ block_sums, int nblocks) {
    __shared__ int lds[SCAN_BLOCK];
    const int t = threadIdx.x;
    int v = (t < nblocks) ? block_sums[t] : 0;
    lds[t] = v;
    __syncthreads();
    for (int off = 1; off < SCAN_BLOCK; off <<= 1) {
        int add = (t >= off) ? lds[t - off] : 0;
        __syncthreads();
        lds[t] += add;
        __syncthreads();
    }
    if (t < nblocks) block_sums[t] = lds[t] - v;   // inclusive -> exclusive
}

// ---------- Pass 3: per-element rank -> dst[i] = output row of input row i ----------
__global__ __launch_bounds__(SCAN_BLOCK)
void dps_rank(const int* __restrict__ parts,
              const int* __restrict__ index0,
              const int* __restrict__ index1,
              const int* __restrict__ block_excl,
              int n, int* __restrict__ dst) {
    const int t  = threadIdx.x;
    const int e0 = blockIdx.x * CHUNK + t * EPT;
    int vals[EPT];
    int s = 0;
    if (e0 + EPT <= n) {
        const int4* p4 = reinterpret_cast<const int4*>(parts + e0);
        #pragma unroll
        for (int k = 0; k < EPT / 4; ++k) {
            int4 v = p4[k];
            vals[k * 4 + 0] = v.x; vals[k * 4 + 1] = v.y;
            vals[k * 4 + 2] = v.z; vals[k * 4 + 3] = v.w;
            s += v.x + v.y + v.z + v.w;
        }
    } else {
        for (int j = 0; j < EPT; ++j) {
            int i = e0 + j;
            vals[j] = (i < n) ? parts[i] : 0;
            s += vals[j];
        }
    }
    __shared__ int lds[SCAN_BLOCK];
    lds[t] = s;
    __syncthreads();
    for (int off = 1; off < SCAN_BLOCK; off <<= 1) {
        int add = (t >= off) ? lds[t - off] : 0;
        __syncthreads();
        lds[t] += add;
        __syncthreads();
    }
    int ones_before = block_excl[blockIdx.x] + (lds[t] - s);
    int dv[EPT];
    #pragma unroll
    for (int j = 0; j < EPT; ++j) {
        int i = e0 + j;
        if (i < n) {
            dv[j] = vals[j] ? index1[ones_before] : index0[i - ones_before];
            ones_before += vals[j];
        }
    }
    // streaming (coalesced-per-thread-chunk) write of dst
    if (e0 + EPT <= n) {
        int4* d4 = reinterpret_cast<int4*>(dst + e0);
        #pragma unroll
        for (int k = 0; k < EPT / 4; ++k)
            d4[k] = make_int4(dv[k*4+0], dv[k*4+1], dv[k*4+2], dv[k*4+3]);
    } else {
        for (int j = 0; j < EPT; ++j) {
            int i = e0 + j;
            if (i < n) dst[i] = dv[j];
        }
    }
}

// ---------- Pass 4: scatter copy — streaming read, scattered 256B write ----------
__global__ __launch_bounds__(256)
void dps_scatter(const float4* __restrict__ data4,
                 const int* __restrict__ dst,
                 float4* __restrict__ out4,
                 long total4) {
    long tid = (long)blockIdx.x * blockDim.x + threadIdx.x;
    if (tid >= total4) return;
    int row = (int)(tid >> 4);          // input row
    int q   = (int)(tid & 15);          // float4 within row
    float4 v = data4[tid];              // perfectly coalesced streaming read
    int dr   = dst[row];                // broadcast across the row's 16 lanes
    out4[((long)dr << 4) + q] = v;      // 256B-granular scattered write
}

extern "C" void kernel_launch(void* const* d_in, const int* in_sizes, int n_in,
                              void* d_out, int out_size, void* d_ws, size_t ws_size,
                              hipStream_t stream) {
    const float* data   = (const float*)d_in[0];
    const int*   parts  = (const int*)d_in[1];
    const int*   index0 = (const int*)d_in[2];
    const int*   index1 = (const int*)d_in[3];
    const int n = in_sizes[1];

    int* dst        = (int*)d_ws;              // n ints
    int* block_sums = dst + n;                 // nchunks ints

    const int nchunks = (n + CHUNK - 1) / CHUNK;   // 256 for n = 1<<20

    dps_count<<<nchunks, SCAN_BLOCK, 0, stream>>>(parts, n, block_sums);
    dps_scan <<<1,       SCAN_BLOCK, 0, stream>>>(block_sums, nchunks);
    dps_rank <<<nchunks, SCAN_BLOCK, 0, stream>>>(parts, index0, index1, block_sums, n, dst);

    const long total4 = (long)n << 4;          // n * (64/4)
    const int  blocks = (int)((total4 + 255) / 256);
    dps_scatter<<<blocks, 256, 0, stream>>>((const float4*)data, dst, (float4*)d_out, total4);
}